// Round 2
// baseline (827.956 us; speedup 1.0000x reference)
//
#include <hip/hip_runtime.h>

// Fused NeRF-MLP: sigmas = softplus(...)*mask, rgbs = sigmoid(...)
// 4096 blocks x 512 thr (8 waves), 64 rows/block, MFMA 16x16x32 bf16.
// Compute is "transposed": A = W^T (out-channels x K), B = activations
// (K x rows). D lane layout: ch = seg*4+j, row = lane&15  (guide §3, m89).
// Round 2: MT 128->64 => LDS 67.6KB => 2 blocks/CU (occupancy 24%->~50%);
// v_cvt_pk_bf16_f32 for f32->bf16; global K-half issued first in L2/L3.

typedef __bf16 bf16x8 __attribute__((ext_vector_type(8)));
typedef float  f32x4  __attribute__((ext_vector_type(4)));
typedef short  short8 __attribute__((ext_vector_type(8)));

#define NROWS (8192 * 32)
#define MT 64
#define RS 264  // LDS row stride in bf16 elems (528 B: 4-bank row shift -> 2-way max, free)

// packed-weight section offsets (bf16 elems) in d_ws
#define P0B   0        // W0^T   K=64(pad from 63), OUT=256 : 16384
#define P1B   16384    // W1     K=256,  OUT=256            : 65536
#define P2B   81920    // W2     K=512,  OUT=256            : 131072
#define PSB   212992   // Ws     K=256,  OUT=16(pad from 1) : 4096
#define P3B   217088   // W3     K=512,  OUT=256            : 131072
#define P4AB  348160   // W4[:256]       K=256, OUT=256     : 65536
#define P4BB  413696   // W4[256:283]    K=32(pad 27)       : 8192
#define PRB   421888   // Wr     K=256,  OUT=16(pad from 3) : 4096
#define PTOT  425984

__device__ __forceinline__ unsigned short f2bf(float f) {
  unsigned u = __builtin_bit_cast(unsigned, f);
  u += 0x7fffu + ((u >> 16) & 1u);   // RNE
  return (unsigned short)(u >> 16);
}
// D.lo16 = bf16(lo), D.hi16 = bf16(hi) -- single VALU op (no builtin on gfx950)
__device__ __forceinline__ unsigned cvt_pk(float lo, float hi) {
  unsigned r;
  asm("v_cvt_pk_bf16_f32 %0, %1, %2" : "=v"(r) : "v"(lo), "v"(hi));
  return r;
}
__device__ __forceinline__ bf16x8 as_bf(short8 s) {
  return __builtin_bit_cast(bf16x8, s);
}

// ---------------- pre-pass: pack weights to bf16 fragment layout ------------
// pack[((kt*OUTP + o)*4 + seg)*8 + j] = W[kt*32 + seg*8 + j][o]
__global__ void prep_pack(const float* __restrict__ W0, const float* __restrict__ W1,
                          const float* __restrict__ W2, const float* __restrict__ Ws,
                          const float* __restrict__ W3, const float* __restrict__ W4,
                          const float* __restrict__ Wr, const float* __restrict__ app,
                          const float* __restrict__ b4,
                          unsigned short* __restrict__ pack, float* __restrict__ b4p)
{
  int gid = blockIdx.x * 256 + threadIdx.x;
  if (gid < PTOT) {
    const float* W; int OUTP, OUTR, Kreal, base, krow = 0;
    if      (gid < P1B)  { W = W0; OUTP = 256; OUTR = 256; Kreal = 63;  base = P0B; }
    else if (gid < P2B)  { W = W1; OUTP = 256; OUTR = 256; Kreal = 256; base = P1B; }
    else if (gid < PSB)  { W = W2; OUTP = 256; OUTR = 256; Kreal = 512; base = P2B; }
    else if (gid < P3B)  { W = Ws; OUTP = 16;  OUTR = 1;   Kreal = 256; base = PSB; }
    else if (gid < P4AB) { W = W3; OUTP = 256; OUTR = 256; Kreal = 512; base = P3B; }
    else if (gid < P4BB) { W = W4; OUTP = 256; OUTR = 256; Kreal = 256; base = P4AB; }
    else if (gid < PRB)  { W = W4; OUTP = 256; OUTR = 256; Kreal = 27;  base = P4BB; krow = 256; }
    else                 { W = Wr; OUTP = 16;  OUTR = 3;   Kreal = 256; base = PRB; }
    int local = gid - base;
    int j   = local & 7;
    int seg = (local >> 3) & 3;
    int rest = local >> 5;
    int o  = rest & (OUTP - 1);
    int kt = rest >> ((OUTP == 256) ? 8 : 4);
    int k  = kt * 32 + seg * 8 + j;
    float v = 0.f;
    if (k < Kreal && o < OUTR) v = W[(long)(k + krow) * OUTR + o];
    pack[gid] = f2bf(v);
  } else if (gid < PTOT + 256) {
    // b4' = b4 + app @ W4[283:331]
    int o = gid - PTOT;
    float a = b4[o];
    for (int i = 0; i < 48; ++i) a += app[i] * W4[(long)(283 + i) * 256 + o];
    b4p[o] = a;
  }
}

// ---------------- main fused kernel ----------------------------------------
__global__ __launch_bounds__(512, 4)
void nerf_fused(const float* __restrict__ pos, const float* __restrict__ dirs,
                const float* __restrict__ gemo, const float* __restrict__ color,
                const float* __restrict__ mask,
                const unsigned short* __restrict__ wp,
                const float* __restrict__ b0, const float* __restrict__ b1,
                const float* __restrict__ b2, const float* __restrict__ bsv,
                const float* __restrict__ b3, const float* __restrict__ b4p,
                const float* __restrict__ brv,
                float* __restrict__ osig, float* __restrict__ orgb)
{
  extern __shared__ unsigned short smem[];
  unsigned short* buf0 = smem;            // [64][RS]
  unsigned short* buf1 = smem + MT * RS;  // [64][RS]

  const int tid  = (int)threadIdx.x;
  const int w    = tid >> 6;
  const int lane = tid & 63;
  const int l16  = lane & 15;
  const int seg  = lane >> 4;
  const int chb  = (w >> 1) * 64;   // 4 channel-groups of 64
  const int rwb  = (w & 1) * 32;    // 2 row-groups of 32
  const long R0  = (long)blockIdx.x * MT;

  f32x4 acc[4][2];

  auto ldA = [&](int baseElems, int OUTP, int o, int kt) -> bf16x8 {
    const bf16x8* p = (const bf16x8*)(wp + baseElems);
    return p[(kt * OUTP + o) * 4 + seg];
  };
  auto ldB_lds = [&](const unsigned short* buf, int rt, int kt) -> bf16x8 {
    int row = rwb + rt * 16 + l16;
    return *(const bf16x8*)(buf + row * RS + kt * 32 + seg * 8);
  };
  auto ldB_g256 = [&](const float* __restrict__ p, int rt, int ktl) -> bf16x8 {
    long row = R0 + rwb + rt * 16 + l16;
    const float4* q = (const float4*)(p + row * 256 + ktl * 32 + seg * 8);
    float4 x = q[0], y = q[1];
    short8 s;
    unsigned u0 = cvt_pk(x.x, x.y), u1 = cvt_pk(x.z, x.w);
    unsigned u2 = cvt_pk(y.x, y.y), u3 = cvt_pk(y.z, y.w);
    s[0] = (short)(u0 & 0xffff); s[1] = (short)(u0 >> 16);
    s[2] = (short)(u1 & 0xffff); s[3] = (short)(u1 >> 16);
    s[4] = (short)(u2 & 0xffff); s[5] = (short)(u2 >> 16);
    s[6] = (short)(u3 & 0xffff); s[7] = (short)(u3 >> 16);
    return as_bf(s);
  };
  auto ldB_gen = [&](const float* __restrict__ p, int stride, int Kreal,
                     int rt, int ktl) -> bf16x8 {
    long row = R0 + rwb + rt * 16 + l16;
    const float* q = p + row * stride;
    int k0 = ktl * 32 + seg * 8;
    short8 s;
#pragma unroll
    for (int j = 0; j < 8; ++j) {
      float v = (k0 + j < Kreal) ? q[k0 + j] : 0.0f;
      s[j] = (short)f2bf(v);
    }
    return as_bf(s);
  };
  auto initAcc = [&](const float* __restrict__ b) {
#pragma unroll
    for (int ct = 0; ct < 4; ++ct) {
      float4 bv = *(const float4*)(b + chb + ct * 16 + seg * 4);
      f32x4 t; t[0] = bv.x; t[1] = bv.y; t[2] = bv.z; t[3] = bv.w;
#pragma unroll
      for (int rt = 0; rt < 2; ++rt) acc[ct][rt] = t;
    }
  };
  auto storeAct = [&](unsigned short* __restrict__ buf) {
#pragma unroll
    for (int ct = 0; ct < 4; ++ct)
#pragma unroll
      for (int rt = 0; rt < 2; ++rt) {
        int row = rwb + rt * 16 + l16;
        int ch  = chb + ct * 16 + seg * 4;
        f32x4 v = acc[ct][rt];
        uint2 u;
        u.x = cvt_pk(fmaxf(v[0], 0.f), fmaxf(v[1], 0.f));
        u.y = cvt_pk(fmaxf(v[2], 0.f), fmaxf(v[3], 0.f));
        *(uint2*)(buf + row * RS + ch) = u;  // ds_write_b64
      }
  };

#define GSTEP(ABASE, kt, BLOADER)                                              \
  {                                                                            \
    bf16x8 Bf[2];                                                              \
    _Pragma("unroll") for (int rt = 0; rt < 2; ++rt) Bf[rt] = BLOADER;         \
    _Pragma("unroll") for (int ct = 0; ct < 4; ++ct) {                         \
      bf16x8 Af = ldA(ABASE, 256, chb + ct * 16 + l16, kt);                    \
      _Pragma("unroll") for (int rt = 0; rt < 2; ++rt)                         \
        acc[ct][rt] = __builtin_amdgcn_mfma_f32_16x16x32_bf16(                 \
            Af, Bf[rt], acc[ct][rt], 0, 0, 0);                                 \
    }                                                                          \
  }

  // ---- L0: d0 = relu(pos @ W0 + b0) -> buf0
  initAcc(b0);
  GSTEP(P0B, 0, ldB_gen(pos, 63, 63, rt, 0));
  GSTEP(P0B, 1, ldB_gen(pos, 63, 63, rt, 1));
  storeAct(buf0);
  __syncthreads();

  // ---- L1: d1 = relu(d0 @ W1 + b1) -> buf1
  initAcc(b1);
#pragma unroll
  for (int kt = 0; kt < 8; ++kt) GSTEP(P1B, kt, ldB_lds(buf0, rt, kt));
  storeAct(buf1);
  __syncthreads();

  // ---- L2: d2 = relu([d1|gemo] @ W2 + b2) -> buf0   (global half first)
  initAcc(b2);
#pragma unroll
  for (int kt = 8; kt < 16; ++kt) GSTEP(P2B, kt, ldB_g256(gemo, rt, kt - 8));
#pragma unroll
  for (int kt = 0; kt < 8; ++kt) GSTEP(P2B, kt, ldB_lds(buf1, rt, kt));
  storeAct(buf0);
  __syncthreads();

  // ---- sigma head: softplus(d2 @ Ws + bs) * mask  (waves 0..3, 16 rows each)
  if (w < 4) {
    f32x4 h; h[0] = (seg == 0) ? bsv[0] : 0.f; h[1] = 0.f; h[2] = 0.f; h[3] = 0.f;
#pragma unroll
    for (int kt = 0; kt < 8; ++kt) {
      bf16x8 Bf = *(const bf16x8*)(buf0 + (w * 16 + l16) * RS + kt * 32 + seg * 8);
      bf16x8 Af = ldA(PSB, 16, l16, kt);
      h = __builtin_amdgcn_mfma_f32_16x16x32_bf16(Af, Bf, h, 0, 0, 0);
    }
    if (seg == 0) {
      long row = R0 + w * 16 + l16;
      float x = h[0];
      float sp = fmaxf(x, 0.f) + log1pf(expf(-fabsf(x)));
      osig[row] = sp * mask[row];
    }
  }
  __syncthreads();

  // ---- L3: d3 = relu([d1|color] @ W3 + b3) -> buf0  (global half first)
  initAcc(b3);
#pragma unroll
  for (int kt = 8; kt < 16; ++kt) GSTEP(P3B, kt, ldB_g256(color, rt, kt - 8));
#pragma unroll
  for (int kt = 0; kt < 8; ++kt) GSTEP(P3B, kt, ldB_lds(buf1, rt, kt));
  storeAct(buf0);
  __syncthreads();

  // ---- L4: d4 = relu([d3|dir|app] @ W4 + b4') -> buf1   (app folded into b4')
  initAcc(b4p);
  GSTEP(P4BB, 0, ldB_gen(dirs, 27, 27, rt, 0));
#pragma unroll
  for (int kt = 0; kt < 8; ++kt) GSTEP(P4AB, kt, ldB_lds(buf0, rt, kt));
  storeAct(buf1);
  __syncthreads();

  // ---- rgb head: sigmoid(d4 @ Wr + br)  (waves 0..3, 16 rows each)
  if (w < 4) {
    f32x4 h;
    h[0] = (seg == 0) ? brv[0] : 0.f;
    h[1] = (seg == 0) ? brv[1] : 0.f;
    h[2] = (seg == 0) ? brv[2] : 0.f;
    h[3] = 0.f;
#pragma unroll
    for (int kt = 0; kt < 8; ++kt) {
      bf16x8 Bf = *(const bf16x8*)(buf1 + (w * 16 + l16) * RS + kt * 32 + seg * 8);
      bf16x8 Af = ldA(PRB, 16, l16, kt);
      h = __builtin_amdgcn_mfma_f32_16x16x32_bf16(Af, Bf, h, 0, 0, 0);
    }
    if (seg == 0) {
      long row = R0 + w * 16 + l16;
      orgb[row * 3 + 0] = 1.f / (1.f + expf(-h[0]));
      orgb[row * 3 + 1] = 1.f / (1.f + expf(-h[1]));
      orgb[row * 3 + 2] = 1.f / (1.f + expf(-h[2]));
    }
  }
#undef GSTEP
}

extern "C" void kernel_launch(void* const* d_in, const int* in_sizes, int n_in,
                              void* d_out, int out_size, void* d_ws, size_t ws_size,
                              hipStream_t stream) {
  const float* pos   = (const float*)d_in[0];
  const float* dirs  = (const float*)d_in[1];
  const float* app   = (const float*)d_in[2];
  const float* gemo  = (const float*)d_in[3];
  const float* color = (const float*)d_in[4];
  const float* mask  = (const float*)d_in[5];
  // d_in[6] = num_inters (fixed 32, shapes are static)
  const float* W0 = (const float*)d_in[7];   const float* b0 = (const float*)d_in[8];
  const float* W1 = (const float*)d_in[9];   const float* b1 = (const float*)d_in[10];
  const float* W2 = (const float*)d_in[11];  const float* b2 = (const float*)d_in[12];
  const float* Ws = (const float*)d_in[13];  const float* bs = (const float*)d_in[14];
  const float* W3 = (const float*)d_in[15];  const float* b3 = (const float*)d_in[16];
  const float* W4 = (const float*)d_in[17];  const float* b4 = (const float*)d_in[18];
  const float* Wr = (const float*)d_in[19];  const float* br = (const float*)d_in[20];

  unsigned short* pack = (unsigned short*)d_ws;
  float* b4p = (float*)((char*)d_ws + (size_t)PTOT * 2);  // 16B-aligned

  float* osig = (float*)d_out;
  float* orgb = osig + NROWS;

  prep_pack<<<dim3((PTOT + 256 + 255) / 256), dim3(256), 0, stream>>>(
      W0, W1, W2, Ws, W3, W4, Wr, app, b4, pack, b4p);

  const int smem_bytes = 2 * MT * RS * 2;  // 67584 B
  hipFuncSetAttribute((const void*)nerf_fused,
                      hipFuncAttributeMaxDynamicSharedMemorySize, smem_bytes);

  nerf_fused<<<dim3(NROWS / MT), dim3(512), smem_bytes, stream>>>(
      pos, dirs, gemo, color, mask, pack,
      b0, b1, b2, bs, b3, b4p, br, osig, orgb);
}

// Round 3
// 601.377 us; speedup vs baseline: 1.3768x; 1.3768x over previous
//
#include <hip/hip_runtime.h>

// Fused NeRF-MLP. Round 3: 4 waves/block (256 thr), 64 rows/block.
// Each wave: 64 out-ch (chb=w*64) x all 64 rows -> acc[4][4], 16 MFMA per
// K32-step fed by 4 A-loads (global/L2, disjoint per wave) + 4 B-loads.
// Explicit 2-deep register prefetch for HBM B-halves (gemo/color);
// per-block K-rotation de-lockesteps L2 weight-line contention.

typedef __bf16 bf16x8 __attribute__((ext_vector_type(8)));
typedef float  f32x4  __attribute__((ext_vector_type(4)));
typedef short  short8 __attribute__((ext_vector_type(8)));

#define NROWS (8192 * 32)
#define MT 64
#define RS 264  // LDS act row stride (528 B -> 4-bank row step, ~2-way max: free)

// packed-weight section offsets (bf16 elems) in d_ws
#define P0B   0        // W0^T   K=64(pad 63),  OUT=256 : 16384
#define P1B   16384    // W1     K=256, OUT=256          : 65536
#define P2B   81920    // W2     K=512, OUT=256          : 131072
#define PSB   212992   // Ws     K=256, OUT=16(pad 1)    : 4096
#define P3B   217088   // W3     K=512, OUT=256          : 131072
#define P4AB  348160   // W4[:256]      K=256, OUT=256   : 65536
#define P4BB  413696   // W4[256:283]   K=32(pad 27)     : 8192
#define PRB   421888   // Wr     K=256, OUT=16(pad 3)    : 4096
#define PTOT  425984

__device__ __forceinline__ unsigned short f2bf(float f) {
  unsigned u = __builtin_bit_cast(unsigned, f);
  u += 0x7fffu + ((u >> 16) & 1u);   // RNE
  return (unsigned short)(u >> 16);
}
__device__ __forceinline__ unsigned cvt_pk(float lo, float hi) {
  unsigned r;
  asm("v_cvt_pk_bf16_f32 %0, %1, %2" : "=v"(r) : "v"(lo), "v"(hi));
  return r;
}
__device__ __forceinline__ bf16x8 cvt8(float4 x, float4 y) {
  unsigned u0 = cvt_pk(x.x, x.y), u1 = cvt_pk(x.z, x.w);
  unsigned u2 = cvt_pk(y.x, y.y), u3 = cvt_pk(y.z, y.w);
  short8 s;
  s[0] = (short)(u0 & 0xffff); s[1] = (short)(u0 >> 16);
  s[2] = (short)(u1 & 0xffff); s[3] = (short)(u1 >> 16);
  s[4] = (short)(u2 & 0xffff); s[5] = (short)(u2 >> 16);
  s[6] = (short)(u3 & 0xffff); s[7] = (short)(u3 >> 16);
  return __builtin_bit_cast(bf16x8, s);
}
__device__ __forceinline__ bf16x8 as_bf(short8 s) {
  return __builtin_bit_cast(bf16x8, s);
}

// ---------------- pre-pass: pack weights to bf16 fragment layout ------------
// pack[((kt*OUTP + o)*4 + seg)*8 + j] = W[kt*32 + seg*8 + j][o]
__global__ void prep_pack(const float* __restrict__ W0, const float* __restrict__ W1,
                          const float* __restrict__ W2, const float* __restrict__ Ws,
                          const float* __restrict__ W3, const float* __restrict__ W4,
                          const float* __restrict__ Wr, const float* __restrict__ app,
                          const float* __restrict__ b4,
                          unsigned short* __restrict__ pack, float* __restrict__ b4p)
{
  int gid = blockIdx.x * 256 + threadIdx.x;
  if (gid < PTOT) {
    const float* W; int OUTP, OUTR, Kreal, base, krow = 0;
    if      (gid < P1B)  { W = W0; OUTP = 256; OUTR = 256; Kreal = 63;  base = P0B; }
    else if (gid < P2B)  { W = W1; OUTP = 256; OUTR = 256; Kreal = 256; base = P1B; }
    else if (gid < PSB)  { W = W2; OUTP = 256; OUTR = 256; Kreal = 512; base = P2B; }
    else if (gid < P3B)  { W = Ws; OUTP = 16;  OUTR = 1;   Kreal = 256; base = PSB; }
    else if (gid < P4AB) { W = W3; OUTP = 256; OUTR = 256; Kreal = 512; base = P3B; }
    else if (gid < P4BB) { W = W4; OUTP = 256; OUTR = 256; Kreal = 256; base = P4AB; }
    else if (gid < PRB)  { W = W4; OUTP = 256; OUTR = 256; Kreal = 27;  base = P4BB; krow = 256; }
    else                 { W = Wr; OUTP = 16;  OUTR = 3;   Kreal = 256; base = PRB; }
    int local = gid - base;
    int j   = local & 7;
    int seg = (local >> 3) & 3;
    int rest = local >> 5;
    int o  = rest & (OUTP - 1);
    int kt = rest >> ((OUTP == 256) ? 8 : 4);
    int k  = kt * 32 + seg * 8 + j;
    float v = 0.f;
    if (k < Kreal && o < OUTR) v = W[(long)(k + krow) * OUTR + o];
    pack[gid] = f2bf(v);
  } else if (gid < PTOT + 256) {
    int o = gid - PTOT;
    float a = b4[o];
    for (int i = 0; i < 48; ++i) a += app[i] * W4[(long)(283 + i) * 256 + o];
    b4p[o] = a;
  }
}

// ---------------- main fused kernel ----------------------------------------
__global__ __launch_bounds__(256, 2)
void nerf_fused(const float* __restrict__ pos, const float* __restrict__ dirs,
                const float* __restrict__ gemo, const float* __restrict__ color,
                const float* __restrict__ mask,
                const unsigned short* __restrict__ wp,
                const float* __restrict__ b0, const float* __restrict__ b1,
                const float* __restrict__ b2, const float* __restrict__ bsv,
                const float* __restrict__ b3, const float* __restrict__ b4p,
                const float* __restrict__ brv,
                float* __restrict__ osig, float* __restrict__ orgb)
{
  extern __shared__ unsigned short smem[];
  unsigned short* buf0 = smem;            // [64][RS]
  unsigned short* buf1 = smem + MT * RS;  // [64][RS]

  const int tid  = (int)threadIdx.x;
  const int w    = tid >> 6;
  const int lane = tid & 63;
  const int l16  = lane & 15;
  const int seg  = lane >> 4;
  const int chb  = w * 64;              // 4 disjoint 64-ch slices
  const long R0  = (long)blockIdx.x * MT;
  const int rot  = (int)(blockIdx.x & 7);

  f32x4 acc[4][4];

  auto ldA = [&](int baseElems, int OUTP, int o, int kt) -> bf16x8 {
    const bf16x8* p = (const bf16x8*)(wp + baseElems);
    return p[(kt * OUTP + o) * 4 + seg];
  };
  auto ldB_lds = [&](const unsigned short* buf, int rt, int kt) -> bf16x8 {
    int row = rt * 16 + l16;
    return *(const bf16x8*)(buf + row * RS + kt * 32 + seg * 8);
  };
  auto ldB_gen = [&](const float* __restrict__ p, int stride, int Kreal,
                     int rt, int ktl) -> bf16x8 {
    long row = R0 + rt * 16 + l16;
    const float* q = p + row * stride;
    int k0 = ktl * 32 + seg * 8;
    short8 s;
#pragma unroll
    for (int j = 0; j < 8; ++j) {
      float v = (k0 + j < Kreal) ? q[k0 + j] : 0.0f;
      s[j] = (short)f2bf(v);
    }
    return as_bf(s);
  };
  auto initAcc = [&](const float* __restrict__ b) {
#pragma unroll
    for (int ct = 0; ct < 4; ++ct) {
      float4 bv = *(const float4*)(b + chb + ct * 16 + seg * 4);
      f32x4 t; t[0] = bv.x; t[1] = bv.y; t[2] = bv.z; t[3] = bv.w;
#pragma unroll
      for (int rt = 0; rt < 4; ++rt) acc[ct][rt] = t;
    }
  };
  auto storeAct = [&](unsigned short* __restrict__ buf) {
#pragma unroll
    for (int ct = 0; ct < 4; ++ct)
#pragma unroll
      for (int rt = 0; rt < 4; ++rt) {
        int row = rt * 16 + l16;
        int ch  = chb + ct * 16 + seg * 4;
        f32x4 v = acc[ct][rt];
        uint2 u;
        u.x = cvt_pk(fmaxf(v[0], 0.f), fmaxf(v[1], 0.f));
        u.y = cvt_pk(fmaxf(v[2], 0.f), fmaxf(v[3], 0.f));
        *(uint2*)(buf + row * RS + ch) = u;  // ds_write_b64
      }
  };

// one K32 step: 4 B-frags + 4 A-loads -> 16 MFMA
#define GSTEP(ABASE, kt, BLOADER)                                              \
  {                                                                            \
    bf16x8 Bf[4];                                                              \
    _Pragma("unroll") for (int rt = 0; rt < 4; ++rt) Bf[rt] = BLOADER;         \
    _Pragma("unroll") for (int ct = 0; ct < 4; ++ct) {                         \
      bf16x8 Af = ldA(ABASE, 256, chb + ct * 16 + l16, kt);                    \
      _Pragma("unroll") for (int rt = 0; rt < 4; ++rt)                         \
        acc[ct][rt] = __builtin_amdgcn_mfma_f32_16x16x32_bf16(                 \
            Af, Bf[rt], acc[ct][rt], 0, 0, 0);                                 \
    }                                                                          \
  }

// 8-step half with B from LDS, K-rotated per block
#define LHALF(ABASE, BUF, KTOFF)                                               \
  _Pragma("unroll") for (int i = 0; i < 8; ++i) {                              \
    int kt = (KTOFF) + ((i + rot) & 7);                                        \
    GSTEP(ABASE, kt, ldB_lds(BUF, rt, kt - (KTOFF)));                          \
  }

// 8-step half with B streamed from global f32 [N,256]; 2-deep reg prefetch
#define GHALF(ABASE, P)                                                        \
  {                                                                            \
    float4 pre[2][4][2];                                                       \
    _Pragma("unroll") for (int s = 0; s < 2; ++s) {                            \
      int ktl = (s + rot) & 7;                                                 \
      _Pragma("unroll") for (int rt = 0; rt < 4; ++rt) {                       \
        const float4* q = (const float4*)((P) + (R0 + rt * 16 + l16) * 256 +   \
                                          ktl * 32 + seg * 8);                 \
        pre[s][rt][0] = q[0]; pre[s][rt][1] = q[1];                            \
      }                                                                        \
    }                                                                          \
    _Pragma("unroll") for (int i = 0; i < 8; ++i) {                            \
      int kt = 8 + ((i + rot) & 7);                                            \
      bf16x8 Bf[4];                                                            \
      _Pragma("unroll") for (int rt = 0; rt < 4; ++rt)                         \
        Bf[rt] = cvt8(pre[i & 1][rt][0], pre[i & 1][rt][1]);                   \
      if (i + 2 < 8) {                                                         \
        int ktl = (i + 2 + rot) & 7;                                           \
        _Pragma("unroll") for (int rt = 0; rt < 4; ++rt) {                     \
          const float4* q = (const float4*)((P) + (R0 + rt * 16 + l16) * 256 + \
                                            ktl * 32 + seg * 8);               \
          pre[i & 1][rt][0] = q[0]; pre[i & 1][rt][1] = q[1];                  \
        }                                                                      \
      }                                                                        \
      _Pragma("unroll") for (int ct = 0; ct < 4; ++ct) {                       \
        bf16x8 Af = ldA(ABASE, 256, chb + ct * 16 + l16, kt);                  \
        _Pragma("unroll") for (int rt = 0; rt < 4; ++rt)                       \
          acc[ct][rt] = __builtin_amdgcn_mfma_f32_16x16x32_bf16(               \
              Af, Bf[rt], acc[ct][rt], 0, 0, 0);                               \
      }                                                                        \
    }                                                                          \
  }

  // ---- L0: d0 = relu(pos @ W0 + b0) -> buf0
  initAcc(b0);
  GSTEP(P0B, 0, ldB_gen(pos, 63, 63, rt, 0));
  GSTEP(P0B, 1, ldB_gen(pos, 63, 63, rt, 1));
  storeAct(buf0);
  __syncthreads();

  // ---- L1: d1 = relu(d0 @ W1 + b1) -> buf1
  initAcc(b1);
  LHALF(P1B, buf0, 0);
  storeAct(buf1);
  __syncthreads();

  // ---- L2: d2 = relu([d1|gemo] @ W2 + b2) -> buf0  (HBM half first, prefetched)
  initAcc(b2);
  GHALF(P2B, gemo);
  LHALF(P2B, buf1, 0);
  storeAct(buf0);
  __syncthreads();

  // ---- sigma head: softplus(d2 @ Ws + bs) * mask (wave w -> rows w*16..+15)
  {
    f32x4 h; h[0] = (seg == 0) ? bsv[0] : 0.f; h[1] = 0.f; h[2] = 0.f; h[3] = 0.f;
#pragma unroll
    for (int i = 0; i < 8; ++i) {
      int kt = (i + rot) & 7;
      bf16x8 Bf = *(const bf16x8*)(buf0 + (w * 16 + l16) * RS + kt * 32 + seg * 8);
      bf16x8 Af = ldA(PSB, 16, l16, kt);
      h = __builtin_amdgcn_mfma_f32_16x16x32_bf16(Af, Bf, h, 0, 0, 0);
    }
    if (seg == 0) {
      long row = R0 + w * 16 + l16;
      float x = h[0];
      float sp = fmaxf(x, 0.f) + log1pf(expf(-fabsf(x)));
      osig[row] = sp * mask[row];
    }
  }
  __syncthreads();

  // ---- L3: d3 = relu([d1|color] @ W3 + b3) -> buf0  (HBM half first, prefetched)
  initAcc(b3);
  GHALF(P3B, color);
  LHALF(P3B, buf1, 0);
  storeAct(buf0);
  __syncthreads();

  // ---- L4: d4 = relu([d3|dir|app] @ W4 + b4') -> buf1  (app folded into b4')
  initAcc(b4p);
  GSTEP(P4BB, 0, ldB_gen(dirs, 27, 27, rt, 0));
  LHALF(P4AB, buf0, 0);
  storeAct(buf1);
  __syncthreads();

  // ---- rgb head: sigmoid(d4 @ Wr + br)  (wave w -> rows w*16..+15)
  {
    f32x4 h;
    h[0] = (seg == 0) ? brv[0] : 0.f;
    h[1] = (seg == 0) ? brv[1] : 0.f;
    h[2] = (seg == 0) ? brv[2] : 0.f;
    h[3] = 0.f;
#pragma unroll
    for (int i = 0; i < 8; ++i) {
      int kt = (i + rot) & 7;
      bf16x8 Bf = *(const bf16x8*)(buf1 + (w * 16 + l16) * RS + kt * 32 + seg * 8);
      bf16x8 Af = ldA(PRB, 16, l16, kt);
      h = __builtin_amdgcn_mfma_f32_16x16x32_bf16(Af, Bf, h, 0, 0, 0);
    }
    if (seg == 0) {
      long row = R0 + w * 16 + l16;
      orgb[row * 3 + 0] = 1.f / (1.f + expf(-h[0]));
      orgb[row * 3 + 1] = 1.f / (1.f + expf(-h[1]));
      orgb[row * 3 + 2] = 1.f / (1.f + expf(-h[2]));
    }
  }
#undef GSTEP
#undef LHALF
#undef GHALF
}

extern "C" void kernel_launch(void* const* d_in, const int* in_sizes, int n_in,
                              void* d_out, int out_size, void* d_ws, size_t ws_size,
                              hipStream_t stream) {
  const float* pos   = (const float*)d_in[0];
  const float* dirs  = (const float*)d_in[1];
  const float* app   = (const float*)d_in[2];
  const float* gemo  = (const float*)d_in[3];
  const float* color = (const float*)d_in[4];
  const float* mask  = (const float*)d_in[5];
  // d_in[6] = num_inters (fixed 32, shapes are static)
  const float* W0 = (const float*)d_in[7];   const float* b0 = (const float*)d_in[8];
  const float* W1 = (const float*)d_in[9];   const float* b1 = (const float*)d_in[10];
  const float* W2 = (const float*)d_in[11];  const float* b2 = (const float*)d_in[12];
  const float* Ws = (const float*)d_in[13];  const float* bs = (const float*)d_in[14];
  const float* W3 = (const float*)d_in[15];  const float* b3 = (const float*)d_in[16];
  const float* W4 = (const float*)d_in[17];  const float* b4 = (const float*)d_in[18];
  const float* Wr = (const float*)d_in[19];  const float* br = (const float*)d_in[20];

  unsigned short* pack = (unsigned short*)d_ws;
  float* b4p = (float*)((char*)d_ws + (size_t)PTOT * 2);

  float* osig = (float*)d_out;
  float* orgb = osig + NROWS;

  prep_pack<<<dim3((PTOT + 256 + 255) / 256), dim3(256), 0, stream>>>(
      W0, W1, W2, Ws, W3, W4, Wr, app, b4, pack, b4p);

  const int smem_bytes = 2 * MT * RS * 2;  // 67584 B -> 2 blocks/CU
  hipFuncSetAttribute((const void*)nerf_fused,
                      hipFuncAttributeMaxDynamicSharedMemorySize, smem_bytes);

  nerf_fused<<<dim3(NROWS / MT), dim3(256), smem_bytes, stream>>>(
      pos, dirs, gemo, color, mask, pack,
      b0, b1, b2, bs, b3, b4p, br, osig, orgb);
}